// Round 12
// baseline (162.054 us; speedup 1.0000x reference)
//
#include <hip/hip_runtime.h>

#define H_    128
#define W_    128
#define C_    256
#define PLANE (H_*W_)
#define ND    9
#define NDISP 81
#define TILE  8
#define HALO  4
#define KC    32
#define NSTEP 8
#define NT    10     // band: key rows 2w .. 2w+9 per wave
#define KPSTR 260    // u32 per pair-plane (256 px + 4 pad)
#define SROW  170    // floats per query in sS: 10 rows x 17
#define SLAB  (KC * PLANE * 4)   // bytes per 32-channel slab (2 MB)

typedef __attribute__((ext_vector_type(8))) short short8;
typedef __attribute__((ext_vector_type(4))) float f32x4;
typedef __attribute__((ext_vector_type(4))) unsigned u32x4;

union SharedU {
    unsigned kbuf[2][16 * KPSTR];   // 33.3 KB double-buffered packed K tile
    float sS[2][16 * SROW];         // 21.8 KB epilogue scratch (overlays)
};

__device__ __forceinline__ unsigned cvtpk(float lo, float hi) {
    unsigned r;
    asm("v_cvt_pk_bf16_f32 %0, %1, %2" : "=v"(r) : "v"(lo), "v"(hi));
    return r;
}

#define STAGE_K(COFF) do {                                                    \
    _Pragma("unroll")                                                         \
    for (int j = 0; j < 8; ++j)                                               \
        asm volatile("global_load_dwordx4 %0, %1, %2"                         \
                     : "=v"(kf[j])                                            \
                     : "v"(vkw[j] + (COFF)), "s"(sB64) : "memory");           \
} while (0)

#define STAGE_Q(COFF) do {                                                    \
    _Pragma("unroll")                                                         \
    for (int j = 0; j < 8; ++j)                                               \
        asm volatile("global_load_dword %0, %1, %2"                           \
                     : "=v"(qf[j])                                            \
                     : "v"(vq + (unsigned)(j * PLANE * 4) + (COFF)),          \
                       "s"(fB64) : "memory");                                 \
} while (0)

// common per-thread geometry
#define GEOMETRY()                                                            \
    const int tid  = threadIdx.x;                                             \
    const int lane = tid & 63;                                                \
    const int wv   = tid >> 6;                                                \
    const int bid  = blockIdx.x;                                              \
    const int tile = (bid & 7) * 128 + (bid >> 3);                            \
    const int b  = tile >> 8;                                                 \
    const int by = (tile >> 4) & 15;                                          \
    const int bx = tile & 15;                                                 \
    const int x0 = bx * TILE, y0 = by * TILE;                                 \
    const int ph = bid & 7;                                                   \
    const int g   = lane >> 4;                                                \
    const int kxq = lane & 15;                                                \
    (void)ph; (void)g; (void)kxq; (void)x0; (void)y0; (void)b; (void)wv;

// ======================= full kernel (round 11, verbatim) ===================
__global__ __launch_bounds__(256, 4) void corr_mfma(
    const float* __restrict__ first, const float* __restrict__ second,
    float* __restrict__ out)
{
    __shared__ SharedU sh;
    GEOMETRY();

    const float* fB = first  + (size_t)b * C_ * PLANE;
    const float* sB = second + (size_t)b * C_ * PLANE;
    const unsigned long long fB64 = (unsigned long long)fB;
    const unsigned long long sB64 = (unsigned long long)sB;

    const int krow = lane >> 2;
    const int kcol = (lane & 3) * 4;
    const int gyc  = min(max(y0 - HALO + krow, 0), H_ - 1);
    const int gxc  = min(max(x0 - HALO + kcol, 0), W_ - 4);
    unsigned vkw[8];
    #pragma unroll
    for (int j = 0; j < 8; ++j)
        vkw[j] = (unsigned)((((8 * wv + j) * PLANE) + gyc * W_ + gxc) * 4);

    const int q  = 16 * wv + kxq;
    const int qy = q >> 3, qx = q & 7;
    const unsigned vq = (unsigned)((g * 8 * PLANE + (y0 + qy) * W_ + (x0 + qx)) * 4);

    f32x4 acc[NT];
    #pragma unroll
    for (int i = 0; i < NT; ++i) acc[i] = (f32x4){0.f, 0.f, 0.f, 0.f};

    f32x4 kf[8];
    float qf[8];

    {
        const unsigned c0 = (unsigned)(ph * SLAB);
        STAGE_K(c0);
        STAGE_Q(c0);
    }

    #pragma unroll 1
    for (int s = 0; s < NSTEP; ++s) {
        unsigned* kb = sh.kbuf[s & 1];

        asm volatile("s_waitcnt vmcnt(0)" ::: "memory");
        __builtin_amdgcn_sched_barrier(0);

        #pragma unroll
        for (int j2 = 0; j2 < 4; ++j2) {
            u32x4 w;
            #pragma unroll
            for (int k = 0; k < 4; ++k)
                w[k] = cvtpk(kf[2 * j2][k], kf[2 * j2 + 1][k]);
            *reinterpret_cast<u32x4*>(&kb[(4 * wv + j2) * KPSTR + 4 * lane]) = w;
        }
        union { unsigned u[4]; short8 v; } ua;
        ua.u[0] = cvtpk(qf[0], qf[1]); ua.u[1] = cvtpk(qf[2], qf[3]);
        ua.u[2] = cvtpk(qf[4], qf[5]); ua.u[3] = cvtpk(qf[6], qf[7]);
        __builtin_amdgcn_sched_barrier(0);

        if (s < NSTEP - 1) {
            const unsigned cn = (unsigned)(((s + 1 + ph) & 7) * SLAB);
            STAGE_K(cn);
            STAGE_Q(cn);
        }

        asm volatile("s_waitcnt lgkmcnt(0)" ::: "memory");
        __builtin_amdgcn_sched_barrier(0);
        __builtin_amdgcn_s_barrier();
        __builtin_amdgcn_sched_barrier(0);

        const unsigned* kbl = kb + (4 * g) * KPSTR + kxq;
        #pragma unroll
        for (int nt = 0; nt < NT; ++nt) {
            const unsigned* pb = kbl + (2 * wv + nt) * 16;
            union { unsigned u[4]; short8 v; } ub;
            #pragma unroll
            for (int j = 0; j < 4; ++j)
                ub.u[j] = pb[j * KPSTR];
            acc[nt] = __builtin_amdgcn_mfma_f32_16x16x32_bf16(ua.v, ub.v, acc[nt], 0, 0, 0);
        }
    }

    const float scale = 1.0f / (float)C_;
    #pragma unroll
    for (int round = 0; round < 2; ++round) {
        __syncthreads();
        if ((wv >> 1) == round) {
            float* dst = sh.sS[wv & 1];
            #pragma unroll
            for (int nt = 0; nt < NT; ++nt) {
                #pragma unroll
                for (int r = 0; r < 4; ++r) {
                    const int qi = (lane >> 4) * 4 + r;
                    dst[qi * SROW + nt * 17 + kxq] = acc[nt][r];
                }
            }
        }
        __syncthreads();
        for (int idx = tid; idx < 2 * 16 * NDISP; idx += 256) {
            const int d   = idx >> 5;
            const int qq  = idx & 31;
            const int pp2 = qq >> 4;
            const int qi  = qq & 15;
            const int dy = d / ND, dx = d % ND;
            const int wv2 = round * 2 + pp2;
            const int gqy = 2 * wv2 + (qi >> 3);
            const int gqx = qi & 7;
            const int lr  = (qi >> 3) + dy;
            const int col = gqx + dx;
            const int kyg = y0 + gqy - HALO + dy;
            const int kxg = x0 + gqx - HALO + dx;
            float v = 0.f;
            if ((unsigned)kyg < (unsigned)H_ && (unsigned)kxg < (unsigned)W_)
                v = sh.sS[pp2][qi * SROW + lr * 17 + col] * scale;
            out[((size_t)b * NDISP + d) * PLANE + (size_t)(y0 + gqy) * W_ + (x0 + gqx)] = v;
        }
    }
}

// ======================= probe 1: contiguous stream =========================
__global__ __launch_bounds__(256, 4) void probe_stream(
    const float* __restrict__ a, const float* __restrict__ bsrc,
    float* __restrict__ ws, unsigned wsCap)
{
    const int bid = blockIdx.x;
    const float* src = (bid < 512) ? (bsrc + (size_t)bid * 32768)
                                   : (a + (size_t)(bid - 512) * 32768);
    const float4* p = reinterpret_cast<const float4*>(src);
    float s0 = 0, s1 = 0, s2 = 0, s3 = 0;
    for (int i = threadIdx.x; i < 8192; i += 256) {
        float4 v = p[i];
        s0 += v.x; s1 += v.y; s2 += v.z; s3 += v.w;
    }
    const unsigned gid = bid * 256 + threadIdx.x;
    if (gid < wsCap) ws[gid] = s0 + s1 + s2 + s3;
}

// ======================= probe 2: staging only (no MFMA) ====================
__global__ __launch_bounds__(256, 4) void probe_stage(
    const float* __restrict__ first, const float* __restrict__ second,
    float* __restrict__ ws, unsigned wsCap)
{
    __shared__ SharedU sh;
    GEOMETRY();

    const float* fB = first  + (size_t)b * C_ * PLANE;
    const float* sB = second + (size_t)b * C_ * PLANE;
    const unsigned long long fB64 = (unsigned long long)fB;
    const unsigned long long sB64 = (unsigned long long)sB;

    const int krow = lane >> 2;
    const int kcol = (lane & 3) * 4;
    const int gyc  = min(max(y0 - HALO + krow, 0), H_ - 1);
    const int gxc  = min(max(x0 - HALO + kcol, 0), W_ - 4);
    unsigned vkw[8];
    #pragma unroll
    for (int j = 0; j < 8; ++j)
        vkw[j] = (unsigned)((((8 * wv + j) * PLANE) + gyc * W_ + gxc) * 4);

    const int q  = 16 * wv + kxq;
    const int qy = q >> 3, qx = q & 7;
    const unsigned vq = (unsigned)((g * 8 * PLANE + (y0 + qy) * W_ + (x0 + qx)) * 4);

    f32x4 kf[8];
    float qf[8];
    unsigned chk = 0;

    {
        const unsigned c0 = (unsigned)(ph * SLAB);
        STAGE_K(c0);
        STAGE_Q(c0);
    }

    #pragma unroll 1
    for (int s = 0; s < NSTEP; ++s) {
        unsigned* kb = sh.kbuf[s & 1];

        asm volatile("s_waitcnt vmcnt(0)" ::: "memory");
        __builtin_amdgcn_sched_barrier(0);

        #pragma unroll
        for (int j2 = 0; j2 < 4; ++j2) {
            u32x4 w;
            #pragma unroll
            for (int k = 0; k < 4; ++k)
                w[k] = cvtpk(kf[2 * j2][k], kf[2 * j2 + 1][k]);
            *reinterpret_cast<u32x4*>(&kb[(4 * wv + j2) * KPSTR + 4 * lane]) = w;
        }
        union { unsigned u[4]; short8 v; } ua;
        ua.u[0] = cvtpk(qf[0], qf[1]); ua.u[1] = cvtpk(qf[2], qf[3]);
        ua.u[2] = cvtpk(qf[4], qf[5]); ua.u[3] = cvtpk(qf[6], qf[7]);
        chk ^= ua.u[0] ^ ua.u[1] ^ ua.u[2] ^ ua.u[3];
        __builtin_amdgcn_sched_barrier(0);

        if (s < NSTEP - 1) {
            const unsigned cn = (unsigned)(((s + 1 + ph) & 7) * SLAB);
            STAGE_K(cn);
            STAGE_Q(cn);
        }

        asm volatile("s_waitcnt lgkmcnt(0)" ::: "memory");
        __builtin_amdgcn_sched_barrier(0);
        __builtin_amdgcn_s_barrier();
        __builtin_amdgcn_sched_barrier(0);
    }

    chk ^= sh.kbuf[0][tid] ^ sh.kbuf[1][tid];
    const unsigned gid = 262144u + (unsigned)bid * 256 + tid;
    if (gid < wsCap) ws[gid] = __uint_as_float(chk & 0x7f7f7f7fu);
}

// ======================= probe 3: LDS+MFMA only (no loads), 4 reps ==========
__global__ __launch_bounds__(256, 4) void probe_mfma(
    float* __restrict__ ws, unsigned wsCap)
{
    __shared__ SharedU sh;
    GEOMETRY();

    f32x4 acc[NT];
    #pragma unroll
    for (int i = 0; i < NT; ++i) acc[i] = (f32x4){0.f, 0.f, 0.f, 0.f};

    f32x4 kf[8];
    float qf[8];
    #pragma unroll
    for (int j = 0; j < 8; ++j) {
        #pragma unroll
        for (int k = 0; k < 4; ++k) kf[j][k] = (float)((tid + 4 * j + k) & 7);
        qf[j] = (float)((tid + j) & 7);
    }

    #pragma unroll 1
    for (int rep = 0; rep < 4; ++rep) {
        #pragma unroll 1
        for (int s = 0; s < NSTEP; ++s) {
            unsigned* kb = sh.kbuf[s & 1];
            #pragma unroll
            for (int j2 = 0; j2 < 4; ++j2) {
                u32x4 w;
                #pragma unroll
                for (int k = 0; k < 4; ++k)
                    w[k] = cvtpk(kf[2 * j2][k], kf[2 * j2 + 1][k]);
                *reinterpret_cast<u32x4*>(&kb[(4 * wv + j2) * KPSTR + 4 * lane]) = w;
            }
            union { unsigned u[4]; short8 v; } ua;
            ua.u[0] = cvtpk(qf[0], qf[1]); ua.u[1] = cvtpk(qf[2], qf[3]);
            ua.u[2] = cvtpk(qf[4], qf[5]); ua.u[3] = cvtpk(qf[6], qf[7]);

            asm volatile("s_waitcnt lgkmcnt(0)" ::: "memory");
            __builtin_amdgcn_sched_barrier(0);
            __builtin_amdgcn_s_barrier();
            __builtin_amdgcn_sched_barrier(0);

            const unsigned* kbl = kb + (4 * g) * KPSTR + kxq;
            #pragma unroll
            for (int nt = 0; nt < NT; ++nt) {
                const unsigned* pb = kbl + (2 * wv + nt) * 16;
                union { unsigned u[4]; short8 v; } ub;
                #pragma unroll
                for (int j = 0; j < 4; ++j)
                    ub.u[j] = pb[j * KPSTR];
                acc[nt] = __builtin_amdgcn_mfma_f32_16x16x32_bf16(ua.v, ub.v, acc[nt], 0, 0, 0);
            }
            __builtin_amdgcn_s_barrier();
        }
    }

    float c = 0.f;
    #pragma unroll
    for (int nt = 0; nt < NT; ++nt)
        #pragma unroll
        for (int r = 0; r < 4; ++r) c += acc[nt][r];
    const unsigned gid = 524288u + (unsigned)bid * 256 + tid;
    if (gid < wsCap) ws[gid] = c;
}

extern "C" void kernel_launch(void* const* d_in, const int* in_sizes, int n_in,
                              void* d_out, int out_size, void* d_ws, size_t ws_size,
                              hipStream_t stream) {
    const float* first  = (const float*)d_in[0];
    const float* second = (const float*)d_in[1];
    float* out = (float*)d_out;
    float* ws  = (float*)d_ws;
    const unsigned wsCap = (unsigned)(ws_size / 4);

    dim3 grid(1024);
    dim3 block(256);
    probe_stream<<<grid, block, 0, stream>>>(first, second, ws, wsCap);
    probe_stage <<<grid, block, 0, stream>>>(first, second, ws, wsCap);
    probe_mfma  <<<grid, block, 0, stream>>>(ws, wsCap);
    corr_mfma   <<<grid, block, 0, stream>>>(first, second, out);
}